// Round 1
// baseline (573.582 us; speedup 1.0000x reference)
//
#include <hip/hip_runtime.h>
#include <hip/hip_bf16.h>
#include <cstdint>
#include <cstddef>

// ---------------- types ----------------
typedef __bf16 bf16;
typedef __bf16 bf16x8 __attribute__((ext_vector_type(8)));
typedef __bf16 bf16x4 __attribute__((ext_vector_type(4)));
typedef float  f32x4  __attribute__((ext_vector_type(4)));

// Problem constants
#define TT 24
#define BB 128
#define EE 512
#define HH 512
#define VV 12000
#define VPAD 12032
#define THREEH 1536
#define MTOT (TT*BB)   // 3072

// global -> LDS direct copy, 16B per lane. LDS dest must be linear in lane order.
#define GLDS(gp, lp)                                                              \
  __builtin_amdgcn_global_load_lds(                                               \
      (const __attribute__((address_space(1))) void*)(const void*)(gp),           \
      (__attribute__((address_space(3))) void*)(void*)(lp), 16, 0, 0)

// ---------------- prep kernels ----------------

// X[m][e], m = t*128+b : t==0 -> img[b], else emb[cap[b][t-1]]
__global__ __launch_bounds__(256) void make_x(const float* __restrict__ img,
                                              const int* __restrict__ cap,
                                              const float* __restrict__ emb,
                                              bf16* __restrict__ X) {
  int fidx = blockIdx.x * 256 + threadIdx.x;      // float4 index, 393216 total
  int m  = fidx >> 7;                              // 128 float4 per 512-row
  int e4 = fidx & 127;
  int t = m >> 7, b = m & 127;
  const float* src;
  if (t == 0) src = img + (size_t)b * EE;
  else        src = emb + (size_t)cap[b * TT + (t - 1)] * EE;
  float4 v = *(const float4*)(src + e4 * 4);
  bf16x4 o = { (bf16)v.x, (bf16)v.y, (bf16)v.z, (bf16)v.w };
  *(bf16x4*)(X + (size_t)m * EE + e4 * 4) = o;
}

// fp32 -> bf16 convert with zero-padding of tail region
__global__ __launch_bounds__(256) void conv_pad(const float* __restrict__ src,
                                                bf16* __restrict__ dst,
                                                int nsrc, int ndst) {
  int i = (blockIdx.x * 256 + threadIdx.x) * 4;
  if (i >= ndst) return;
  float4 v = make_float4(0.f, 0.f, 0.f, 0.f);
  if (i + 4 <= nsrc) {
    v = *(const float4*)(src + i);
  } else {
    if (i + 0 < nsrc) v.x = src[i + 0];
    if (i + 1 < nsrc) v.y = src[i + 1];
    if (i + 2 < nsrc) v.z = src[i + 2];
    if (i + 3 < nsrc) v.w = src[i + 3];
  }
  bf16x4 o = { (bf16)v.x, (bf16)v.y, (bf16)v.z, (bf16)v.w };
  *(bf16x4*)(dst + i) = o;
}

// ---------------- bf16 MFMA GEMM: C[m][n] = sum_k A[m][k]*B[n][k] (+bias) ----------------
// A: [M][512] bf16 row-major, B: [Npad][512] bf16 row-major ("B^T" GEMM).
// 128x128 tile, BK=32, 256 threads = 4 waves (2x2), each wave 4x4 16x16x32 frags.
// PERM=1: C row m = t*128+b is written to out[b*T*V + t*V + n], guarded n < Nvalid.
template <int PERM>
__global__ __launch_bounds__(256) void gemm_bt(const bf16* __restrict__ A,
                                               const bf16* __restrict__ Bm,
                                               const float* __restrict__ bias,
                                               float* __restrict__ C,
                                               int N, int Nvalid) {
  const int K = 512;
  __shared__ __align__(16) bf16 Alds[128 * 32];
  __shared__ __align__(16) bf16 Blds[128 * 32];
  const int tid  = threadIdx.x;
  const int lane = tid & 63;
  const int wv   = tid >> 6;
  const int wr   = wv >> 1, wc = wv & 1;
  const int m0 = blockIdx.y * 128, n0 = blockIdx.x * 128;
  const bf16* Ab = A + (size_t)m0 * K;
  const bf16* Bb = Bm + (size_t)n0 * K;
  const int srow = tid >> 2;             // 0..63
  const int skq  = (tid & 3) * 8;        // k offset in elems

  f32x4 acc[4][4];
#pragma unroll
  for (int i = 0; i < 4; i++)
#pragma unroll
    for (int j = 0; j < 4; j++) acc[i][j] = 0.f;

  for (int kt = 0; kt < K; kt += 32) {
    __syncthreads();
    GLDS(Ab + (size_t)srow * K + kt + skq,        Alds + srow * 32 + skq);
    GLDS(Ab + (size_t)(srow + 64) * K + kt + skq, Alds + (srow + 64) * 32 + skq);
    GLDS(Bb + (size_t)srow * K + kt + skq,        Blds + srow * 32 + skq);
    GLDS(Bb + (size_t)(srow + 64) * K + kt + skq, Blds + (srow + 64) * 32 + skq);
    asm volatile("s_waitcnt vmcnt(0)" ::: "memory");
    __syncthreads();

    const int fr = lane & 15, kh = lane >> 4;
    bf16x8 af[4], bfv[4];
#pragma unroll
    for (int i = 0; i < 4; i++)
      af[i] = *(const bf16x8*)(Alds + (wr * 64 + i * 16 + fr) * 32 + kh * 8);
#pragma unroll
    for (int j = 0; j < 4; j++)
      bfv[j] = *(const bf16x8*)(Blds + (wc * 64 + j * 16 + fr) * 32 + kh * 8);
#pragma unroll
    for (int i = 0; i < 4; i++)
#pragma unroll
      for (int j = 0; j < 4; j++)
        acc[i][j] = __builtin_amdgcn_mfma_f32_16x16x32_bf16(af[i], bfv[j], acc[i][j], 0, 0, 0);
  }

  const int fr = lane & 15, fq = lane >> 4;
#pragma unroll
  for (int j = 0; j < 4; j++) {
    int n = n0 + wc * 64 + j * 16 + fr;
    if (n >= Nvalid) continue;
    float bv = bias ? bias[n] : 0.f;
#pragma unroll
    for (int i = 0; i < 4; i++) {
#pragma unroll
      for (int r = 0; r < 4; r++) {
        int m = m0 + wr * 64 + i * 16 + fq * 4 + r;
        float v = acc[i][j][r] + bv;
        size_t off;
        if (PERM) off = (size_t)(m & 127) * (TT * (size_t)VV) + (size_t)(m >> 7) * VV + n;
        else      off = (size_t)m * N + n;
        C[off] = v;
      }
    }
  }
}

// ---------------- GRU step (one t): gh = h_bf16 @ W_hh^T, fused gates ----------------
// grid = 32 blocks, block owns j-slice of 16 H-columns for ALL 3 gates, all 128 batch rows.
// 256 thr = 4 waves; wave -> 32 batch rows (2 m-frags) x 3 gate frags.
__global__ __launch_bounds__(256) void gru_step(const bf16* __restrict__ hbf_in,
                                                const bf16* __restrict__ Whh_b,
                                                const float* __restrict__ gx,
                                                const float* __restrict__ b_hh,
                                                float* __restrict__ h_f32,
                                                bf16* __restrict__ hbf_out,
                                                bf16* __restrict__ hs,
                                                int t) {
  const int K = 512;
  __shared__ __align__(16) bf16 Alds[128 * 32];
  __shared__ __align__(16) bf16 Blds[64 * 32];
  const int tid = threadIdx.x, lane = tid & 63, wv = tid >> 6;
  const int j0 = blockIdx.x * 16;
  const int srow = tid >> 2;
  const int skq  = (tid & 3) * 8;
  // B staging source row: rows 0..47 are W_hh rows {g*512 + j0 + jj}; 48..63 dummy row 0.
  const int bg = srow >> 4, bjj = srow & 15;
  const size_t brow = (srow < 48) ? (size_t)(bg * HH + j0 + bjj) : (size_t)0;

  f32x4 acc[2][3];
#pragma unroll
  for (int i = 0; i < 2; i++)
#pragma unroll
    for (int g = 0; g < 3; g++) acc[i][g] = 0.f;

  for (int kt = 0; kt < K; kt += 32) {
    __syncthreads();
    GLDS(hbf_in + (size_t)srow * K + kt + skq,        Alds + srow * 32 + skq);
    GLDS(hbf_in + (size_t)(srow + 64) * K + kt + skq, Alds + (srow + 64) * 32 + skq);
    GLDS(Whh_b + brow * K + kt + skq,                 Blds + srow * 32 + skq);
    asm volatile("s_waitcnt vmcnt(0)" ::: "memory");
    __syncthreads();

    const int fr = lane & 15, kh = lane >> 4;
    bf16x8 af[2], bfv[3];
#pragma unroll
    for (int mi = 0; mi < 2; mi++)
      af[mi] = *(const bf16x8*)(Alds + (wv * 32 + mi * 16 + fr) * 32 + kh * 8);
#pragma unroll
    for (int g = 0; g < 3; g++)
      bfv[g] = *(const bf16x8*)(Blds + (g * 16 + fr) * 32 + kh * 8);
#pragma unroll
    for (int mi = 0; mi < 2; mi++)
#pragma unroll
      for (int g = 0; g < 3; g++)
        acc[mi][g] = __builtin_amdgcn_mfma_f32_16x16x32_bf16(af[mi], bfv[g], acc[mi][g], 0, 0, 0);
  }

  const int fr = lane & 15, fq = lane >> 4;
  const int j = j0 + fr;
  const float bh0 = b_hh[j], bh1 = b_hh[HH + j], bh2 = b_hh[2 * HH + j];
#pragma unroll
  for (int mi = 0; mi < 2; mi++) {
#pragma unroll
    for (int r = 0; r < 4; r++) {
      int bb = wv * 32 + mi * 16 + fq * 4 + r;      // batch row
      int row = t * BB + bb;
      float hr = acc[mi][0][r] + bh0;
      float hz = acc[mi][1][r] + bh1;
      float hn = acc[mi][2][r] + bh2;
      float xr = gx[(size_t)row * THREEH + j];
      float xz = gx[(size_t)row * THREEH + HH + j];
      float xn = gx[(size_t)row * THREEH + 2 * HH + j];
      float rg = 1.f / (1.f + __expf(-(xr + hr)));
      float zg = 1.f / (1.f + __expf(-(xz + hz)));
      float ng = tanhf(xn + rg * hn);
      float hp = h_f32[(size_t)bb * HH + j];
      float hnew = (1.f - zg) * ng + zg * hp;
      h_f32[(size_t)bb * HH + j] = hnew;
      hbf_out[(size_t)bb * HH + j] = (bf16)hnew;
      hs[(size_t)row * HH + j] = (bf16)hnew;
    }
  }
}

// ---------------- launcher ----------------
extern "C" void kernel_launch(void* const* d_in, const int* in_sizes, int n_in,
                              void* d_out, int out_size, void* d_ws, size_t ws_size,
                              hipStream_t stream) {
  const float* img   = (const float*)d_in[0];
  const int*   cap   = (const int*)d_in[1];
  // d_in[2] = caplen (unused; static T)
  const float* emb   = (const float*)d_in[3];
  const float* W_ih  = (const float*)d_in[4];
  const float* W_hh  = (const float*)d_in[5];
  const float* b_ih  = (const float*)d_in[6];
  const float* b_hh  = (const float*)d_in[7];
  const float* W_out = (const float*)d_in[8];
  const float* b_out = (const float*)d_in[9];
  float* out = (float*)d_out;

  char* ws = (char*)d_ws;
  size_t off = 0;
  auto alloc = [&](size_t bytes) {
    void* p = ws + off;
    off = (off + bytes + 255) & ~(size_t)255;
    return p;
  };
  bf16*  X      = (bf16*)alloc((size_t)MTOT * EE * 2);        // 3.1 MB
  bf16*  Wih_b  = (bf16*)alloc((size_t)THREEH * EE * 2);      // 1.5 MB
  bf16*  Whh_b  = (bf16*)alloc((size_t)THREEH * HH * 2);      // 1.5 MB
  bf16*  Wout_b = (bf16*)alloc((size_t)VPAD * HH * 2);        // 12.3 MB
  float* gx     = (float*)alloc((size_t)MTOT * THREEH * 4);   // 18.9 MB
  bf16*  hs     = (bf16*)alloc((size_t)MTOT * HH * 2);        // 3.1 MB
  float* hf     = (float*)alloc((size_t)BB * HH * 4);         // 256 KB
  bf16*  hb0    = (bf16*)alloc((size_t)BB * HH * 2);          // 128 KB
  bf16*  hb1    = (bf16*)alloc((size_t)BB * HH * 2);          // 128 KB

  // zero h state (fp32 + both bf16 ping-pong buffers; they are contiguous)
  hipMemsetAsync(hf, 0, (size_t)BB * HH * 4 + 2 * (size_t)BB * HH * 2, stream);

  // prep
  make_x<<<dim3(MTOT * EE / 4 / 256), dim3(256), 0, stream>>>(img, cap, emb, X);
  conv_pad<<<dim3(THREEH * EE / 4 / 256), dim3(256), 0, stream>>>(W_ih, Wih_b, THREEH * EE, THREEH * EE);
  conv_pad<<<dim3(THREEH * HH / 4 / 256), dim3(256), 0, stream>>>(W_hh, Whh_b, THREEH * HH, THREEH * HH);
  conv_pad<<<dim3(VPAD * HH / 4 / 256), dim3(256), 0, stream>>>(W_out, Wout_b, VV * HH, VPAD * HH);

  // gx = X @ W_ih^T + b_ih   [3072][1536] fp32
  gemm_bt<0><<<dim3(THREEH / 128, MTOT / 128), dim3(256), 0, stream>>>(
      X, Wih_b, b_ih, gx, THREEH, THREEH);

  // 24 sequential GRU steps
  for (int t = 0; t < TT; ++t) {
    const bf16* hin = (t & 1) ? hb1 : hb0;
    bf16* hout      = (t & 1) ? hb0 : hb1;
    gru_step<<<dim3(HH / 16), dim3(256), 0, stream>>>(hin, Whh_b, gx, b_hh, hf, hout, hs, t);
  }

  // logits = hs @ W_out^T + b_out, permuted store to [B,T,V]
  gemm_bt<1><<<dim3(VPAD / 128, MTOT / 128), dim3(256), 0, stream>>>(
      hs, Wout_b, b_out, out, VV, VV);
}